// Round 6
// baseline (11963.007 us; speedup 1.0000x reference)
//
#include <hip/hip_runtime.h>
#include <math.h>

#define Bn    16
#define Tn    512
#define CENCn 128
#define EMBn  512
#define Hn    512
#define HHn   256
#define Pn    8
#define NTAGn 12
#define G4n   1024   // 4*HH

__device__ __forceinline__ float sigm(float x) { return 1.f / (1.f + __expf(-x)); }
__device__ __forceinline__ float tanh_(float x) { return 2.f / (1.f + __expf(-2.f * x)) - 1.f; }

// ---------------------------------------------------------------------------
// C[M,N] = A[M,K] @ Bm[N,K]^T + b1[N] + b2[N]   (b1/b2 may be null)
// 128x128 tile, BK=16, 256 threads, 8x8 micro-tile, transposed LDS tiles.
// ---------------------------------------------------------------------------
__global__ __launch_bounds__(256) void gemm_tn(
    const float* __restrict__ A, const float* __restrict__ Bm,
    float* __restrict__ C, const float* __restrict__ b1,
    const float* __restrict__ b2, int M, int N, int K)
{
    __shared__ float As[16][132];
    __shared__ float Bs[16][132];
    const int tid = threadIdx.x;
    const int tx = tid & 15, ty = tid >> 4;
    const int m0 = blockIdx.y * 128, n0 = blockIdx.x * 128;

    float acc[8][8];
#pragma unroll
    for (int i = 0; i < 8; i++)
#pragma unroll
        for (int j = 0; j < 8; j++) acc[i][j] = 0.f;

    const int r  = tid >> 2;
    const int cc = (tid & 3) * 4;

    for (int k0 = 0; k0 < K; k0 += 16) {
#pragma unroll
        for (int hh = 0; hh < 2; hh++) {
            const int row = r + hh * 64;
            const float4 va = *(const float4*)(A + (size_t)(m0 + row) * K + k0 + cc);
            As[cc + 0][row] = va.x; As[cc + 1][row] = va.y;
            As[cc + 2][row] = va.z; As[cc + 3][row] = va.w;
            const float4 vb = *(const float4*)(Bm + (size_t)(n0 + row) * K + k0 + cc);
            Bs[cc + 0][row] = vb.x; Bs[cc + 1][row] = vb.y;
            Bs[cc + 2][row] = vb.z; Bs[cc + 3][row] = vb.w;
        }
        __syncthreads();
#pragma unroll
        for (int kk = 0; kk < 16; kk++) {
            const float4 a0 = *(const float4*)&As[kk][ty * 4];
            const float4 a1 = *(const float4*)&As[kk][64 + ty * 4];
            const float4 b0 = *(const float4*)&Bs[kk][tx * 4];
            const float4 b1v = *(const float4*)&Bs[kk][64 + tx * 4];
            const float av[8] = {a0.x, a0.y, a0.z, a0.w, a1.x, a1.y, a1.z, a1.w};
            const float bv[8] = {b0.x, b0.y, b0.z, b0.w, b1v.x, b1v.y, b1v.z, b1v.w};
#pragma unroll
            for (int ii = 0; ii < 8; ii++)
#pragma unroll
                for (int jj = 0; jj < 8; jj++) acc[ii][jj] += av[ii] * bv[jj];
        }
        __syncthreads();
    }

    float bb[8];
#pragma unroll
    for (int jj = 0; jj < 8; jj++) {
        const int col = n0 + ((jj < 4) ? (tx * 4 + jj) : (64 + tx * 4 + jj - 4));
        bb[jj] = (b1 ? b1[col] : 0.f) + (b2 ? b2[col] : 0.f);
    }
#pragma unroll
    for (int ii = 0; ii < 8; ii++) {
        const int row = m0 + ((ii < 4) ? (ty * 4 + ii) : (64 + ty * 4 + ii - 4));
        float4 v0, v1;
        v0.x = acc[ii][0] + bb[0]; v0.y = acc[ii][1] + bb[1];
        v0.z = acc[ii][2] + bb[2]; v0.w = acc[ii][3] + bb[3];
        v1.x = acc[ii][4] + bb[4]; v1.y = acc[ii][5] + bb[5];
        v1.z = acc[ii][6] + bb[6]; v1.w = acc[ii][7] + bb[7];
        *(float4*)(C + (size_t)row * N + n0 + tx * 4) = v0;
        *(float4*)(C + (size_t)row * N + n0 + 64 + tx * 4) = v1;
    }
}

// ---------------------------------------------------------------------------
// Agent-scope generation barrier over nblk blocks (cnt must start at 0; gen
// may start at any value). All inter-block data exchange goes through
// agent-scope atomics, so no reliance on cross-XCD L2 coherence of plain
// stores. __syncthreads before the RMW drains each lane's vmcnt, so all h
// stores are at the coherence point before the release-increment of gen.
// ---------------------------------------------------------------------------
__device__ __forceinline__ void bar_sync(unsigned* cnt, unsigned* gen, unsigned nblk)
{
    __syncthreads();
    if (threadIdx.x == 0) {
        unsigned g0 = __hip_atomic_load(gen, __ATOMIC_RELAXED, __HIP_MEMORY_SCOPE_AGENT);
        unsigned a  = __hip_atomic_fetch_add(cnt, 1u, __ATOMIC_ACQ_REL, __HIP_MEMORY_SCOPE_AGENT);
        if (a + 1u == nblk) {
            __hip_atomic_store(cnt, 0u, __ATOMIC_RELAXED, __HIP_MEMORY_SCOPE_AGENT);
            __hip_atomic_fetch_add(gen, 1u, __ATOMIC_RELEASE, __HIP_MEMORY_SCOPE_AGENT);
        } else {
            unsigned gg;
            do {
                __builtin_amdgcn_s_sleep(2);
                gg = __hip_atomic_load(gen, __ATOMIC_ACQUIRE, __HIP_MEMORY_SCOPE_AGENT);
            } while (gg == g0);
        }
    }
    __syncthreads();
}

// ---------------------------------------------------------------------------
// Persistent encoder scan: one launch per layer, 64 blocks = 2 dirs x 32.
// Block (dir,g) owns h-dims g*8..g*8+7 (32 gate rows), Whh slice in VGPRs
// (loaded once for all 512 steps). h is exchanged per step through a
// double-buffered global buffer with agent-scope atomics; c/h state for the
// owned dims lives in registers of the cell threads (tid<128).
// ---------------------------------------------------------------------------
__global__ __launch_bounds__(256, 1) void enc_scan(
    const float* __restrict__ Gx, const float* __restrict__ WhhF,
    const float* __restrict__ WhhR, const float* __restrict__ h0_l,
    const float* __restrict__ c0_l, float* __restrict__ outbuf,
    const int* __restrict__ lens, float* __restrict__ hx,
    unsigned* __restrict__ bar)
{
    __shared__ float hsh[16 * 288];   // [b][kc:36-word chunks] swizzled (conflict-free b128)
    __shared__ float psh[32 * 129];   // [lr][b][kc] partials, stride 129 (conflict-free)
    const int tid = threadIdx.x;
    const int dir = blockIdx.x >> 5;
    const int g   = blockIdx.x & 31;
    const float* Whh = dir ? WhhR : WhhF;
    unsigned* cnt = bar + dir * 32;
    unsigned* gen = bar + dir * 32 + 16;

    const int kc = tid & 7;
    const int rw = (tid >> 3) & 7;
    const int bs = tid >> 6;

    // Whh slice -> registers (loop-invariant over 512 steps): 4 rows x 32 k
    float4 w4[32];
#pragma unroll
    for (int ri = 0; ri < 4; ri++) {
        const int lr = rw * 4 + ri;
        const int grow = ((lr >> 3) << 8) + g * 8 + (lr & 7);   // q*256 + g*8 + jj
#pragma unroll
        for (int j4 = 0; j4 < 8; j4++)
            w4[ri * 8 + j4] = *(const float4*)(Whh + (size_t)grow * HHn + kc * 32 + j4 * 4);
    }

    // cell-thread persistent state
    const int cb = tid >> 3, cj = tid & 7;
    const int hd = g * 8 + cj;
    float h_reg = 0.f, c_reg = 0.f;
    int lb = 0;
    if (tid < 128) {
        lb = lens[cb];
        h_reg = h0_l[dir * 4096 + cb * 256 + hd];
        c_reg = c0_l[dir * 4096 + cb * 256 + hd];
    }

    const int hpos_k = (tid >> 5) * 36 + (tid & 31);

    for (int t = 0; t < Tn; t++) {
        // ---- prefetch this step's Gx for the cell phase (hide L2/L3 latency)
        float gx0 = 0.f, gx1 = 0.f, gx2 = 0.f, gx3 = 0.f;
        const bool act = (tid < 128) && (t < lb);
        if (act) {
            const int tr_in = dir ? (lb - 1 - t) : t;
            const size_t gbase = ((size_t)tr_in * Bn + cb) * 2048 + dir * 1024 + g * 8 + cj;
            gx0 = Gx[gbase];
            gx1 = Gx[gbase + 256];
            gx2 = Gx[gbase + 512];
            gx3 = Gx[gbase + 768];
        }

        // ---- stage h(t-1) into LDS (swizzled)
        if (t == 0) {
#pragma unroll
            for (int i = 0; i < 16; i++)
                hsh[i * 288 + hpos_k] = h0_l[dir * 4096 + i * 256 + tid];
        } else {
            const float* src = hx + (((t - 1) & 1) * 8192) + dir * 4096;
#pragma unroll
            for (int i = 0; i < 16; i++)
                hsh[i * 288 + hpos_k] =
                    __hip_atomic_load(src + i * 256 + tid, __ATOMIC_RELAXED,
                                      __HIP_MEMORY_SCOPE_AGENT);
        }
        __syncthreads();

        // ---- dot: 4 rows x 4 batches x 32 k per thread, weights in VGPRs
        float acc[4][4];
#pragma unroll
        for (int bl = 0; bl < 4; bl++) {
            const int b = bs * 4 + bl;
            const float4* hrow = (const float4*)(hsh + b * 288 + kc * 36);
            float4 hv[8];
#pragma unroll
            for (int j4 = 0; j4 < 8; j4++) hv[j4] = hrow[j4];
#pragma unroll
            for (int ri = 0; ri < 4; ri++) {
                float s = 0.f;
#pragma unroll
                for (int j4 = 0; j4 < 8; j4++) {
                    const float4 wv = w4[ri * 8 + j4];
                    s += wv.x * hv[j4].x + wv.y * hv[j4].y
                       + wv.z * hv[j4].z + wv.w * hv[j4].w;
                }
                acc[ri][bl] = s;
            }
        }
#pragma unroll
        for (int ri = 0; ri < 4; ri++)
#pragma unroll
            for (int bl = 0; bl < 4; bl++)
                psh[(rw * 4 + ri) * 129 + (bs * 4 + bl) * 8 + kc] = acc[ri][bl];
        __syncthreads();

        // ---- cell (tid<128): reduce 8 partials per gate, LSTM update
        if (act) {
            float s0 = gx0, s1 = gx1, s2 = gx2, s3 = gx3;
            const int pb = cb * 8;
#pragma unroll
            for (int kcc = 0; kcc < 8; kcc++) {
                s0 += psh[(0 * 8 + cj) * 129 + pb + kcc];
                s1 += psh[(1 * 8 + cj) * 129 + pb + kcc];
                s2 += psh[(2 * 8 + cj) * 129 + pb + kcc];
                s3 += psh[(3 * 8 + cj) * 129 + pb + kcc];
            }
            const float c_new = sigm(s1) * c_reg + sigm(s0) * tanh_(s2);
            const float h_new = sigm(s3) * tanh_(c_new);
            c_reg = c_new;
            h_reg = h_new;
            const int trow = dir ? (lb - 1 - t) : t;
            outbuf[((size_t)trow * Bn + cb) * Hn + dir * HHn + hd] = h_new;
        }
        if (tid < 128)
            __hip_atomic_store(hx + ((t & 1) * 8192) + dir * 4096 + cb * 256 + hd,
                               h_reg, __ATOMIC_RELAXED, __HIP_MEMORY_SCOPE_AGENT);

        if (t != Tn - 1) bar_sync(cnt, gen, 32u);
    }
}

// ---------------------------------------------------------------------------
// Segment-scan cell + fused final FC. At k==0 the recurrent term (GT) and
// previous cell state are identically zero, so neither GT nor Cs is read --
// this replaces the Hs/Cs/GT zero-fill memsets entirely.
// ---------------------------------------------------------------------------
__global__ __launch_bounds__(256) void seg_cell(
    const float* __restrict__ GT, const float* __restrict__ Gx,
    float* __restrict__ Hs, float* __restrict__ Cs,
    const float* __restrict__ Wfc, float* __restrict__ outp,
    const int* __restrict__ lens, int k, int dir)
{
    __shared__ float hshs[256];
    const int s = blockIdx.x;
    const int b = s >> 9, t0 = s & 511;
    const int tid = threadIdx.x;
    const int tau = dir ? (t0 - k) : (t0 + k);
    const int tauc = min(max(tau, 0), Tn - 1);
    const size_t grow = ((size_t)(b << 9) + tauc) * G4n;
    const size_t srow = (size_t)s * G4n;
    const size_t hidx = (size_t)s * 256 + tid;

    float gi = Gx[grow + tid];
    float gf = Gx[grow + 256 + tid];
    float gg = Gx[grow + 512 + tid];
    float go = Gx[grow + 768 + tid];
    float cprev = 0.f;
    if (k > 0) {
        gi += GT[srow + tid];
        gf += GT[srow + 256 + tid];
        gg += GT[srow + 512 + tid];
        go += GT[srow + 768 + tid];
        cprev = Cs[hidx];
    }
    const float c_new = sigm(gf) * cprev + sigm(gi) * tanh_(gg);
    const float h_new = sigm(go) * tanh_(c_new);
    Cs[hidx] = c_new;
    Hs[hidx] = h_new;
    hshs[tid] = h_new;
    __syncthreads();

    const int t_out = dir ? t0 : (t0 + k);
    const bool valid = dir ? (t0 >= k && t0 < lens[b])
                           : (t_out < Tn && t_out < lens[b]);
    if (valid && tid < 192) {
        const int n = tid >> 4, l = tid & 15;
        const int off = dir ? 256 : 0;
        float a = 0.f;
#pragma unroll
        for (int e = 0; e < 16; e++)
            a += hshs[l + (e << 4)] * Wfc[n * Hn + off + l + (e << 4)];
        a += __shfl_down(a, 8, 16);
        a += __shfl_down(a, 4, 16);
        a += __shfl_down(a, 2, 16);
        a += __shfl_down(a, 1, 16);
        if (l == 0) {
            const size_t oidx = (((size_t)(b << 9) + t_out) * Pn + k) * NTAGn + n;
            outp[oidx] += a;
        }
    }
}

__global__ __launch_bounds__(256) void transpose_tb(
    const float* __restrict__ in, float* __restrict__ outp)
{
    const int s = blockIdx.x;
    const int b = s >> 9, t = s & 511;
    const int tid = threadIdx.x;
    const float* src = in + (size_t)(t * Bn + b) * Hn;
    float* dst = outp + (size_t)s * Hn;
    dst[tid] = src[tid];
    dst[tid + 256] = src[tid + 256];
}

__global__ __launch_bounds__(256) void init_out(
    float* __restrict__ outp, const float* __restrict__ bfc, int n)
{
    const int i = blockIdx.x * 256 + threadIdx.x;
    if (i < n) outp[i] = bfc[i % NTAGn];
}

// ---------------------------------------------------------------------------
extern "C" void kernel_launch(void* const* d_in, const int* in_sizes, int n_in,
                              void* d_out, int out_size, void* d_ws, size_t ws_size,
                              hipStream_t stream)
{
    (void)in_sizes; (void)n_in; (void)out_size; (void)ws_size;
    const float* x      = (const float*)d_in[0];
    const float* h0     = (const float*)d_in[1];
    const float* c0     = (const float*)d_in[2];
    const float* W_emb  = (const float*)d_in[3];
    const float* b_emb  = (const float*)d_in[4];
    const float* Wih    = (const float*)d_in[5];
    const float* Whh    = (const float*)d_in[6];
    const float* bih    = (const float*)d_in[7];
    const float* bhh    = (const float*)d_in[8];
    const float* Wih_sf = (const float*)d_in[9];
    const float* Whh_sf = (const float*)d_in[10];
    const float* bih_sf = (const float*)d_in[11];
    const float* bhh_sf = (const float*)d_in[12];
    const float* Wih_sr = (const float*)d_in[13];
    const float* Whh_sr = (const float*)d_in[14];
    const float* bih_sr = (const float*)d_in[15];
    const float* bhh_sr = (const float*)d_in[16];
    const float* Wfc    = (const float*)d_in[17];
    const float* bfc    = (const float*)d_in[18];
    const int*   lens   = (const int*)d_in[19];
    float* out = (float*)d_out;
    float* w   = (float*)d_ws;

    // workspace layout (floats)
    float* bufA = w;                  // 4194304  [T*B,512]
    float* bufB = w + 4194304;        // 4194304
    float* G0   = w + 8388608;        // 8388608  [8192,1024] (also low half of Gbig)
    float* G1   = w + 16777216;       // 8388608  (high half of Gbig)
    float* U    = w + 25165824;       // 4194304  [B*T,512]
    float* Hs   = w + 29360128;       // 2097152  [8192,256]
    float* Cs   = w + 31457280;       // 2097152
    float* hx   = w + 33554432;       // 16384  [2][2][16][256] h double-buffer
    unsigned* bar = (unsigned*)(w + 33570816);  // 64 uints
    float* Gbig = G0;                 // [8192,2048] fwd|rev merged encoder gates
    float* GT   = w;                  // 8388608 (alias over bufA+bufB, dead by then)

    const dim3 blk(256);

    // 1. embedding: bufA = x @ W_emb^T + b_emb
    gemm_tn<<<dim3(EMBn / 128, (Tn * Bn) / 128), blk, 0, stream>>>(
        x, W_emb, bufA, b_emb, nullptr, Tn * Bn, EMBn, CENCn);

    // 2. encoder: 2 bidirectional layers, persistent scan kernel per layer
    for (int l = 0; l < 2; l++) {
        const float* Xin = l ? bufB : bufA;
        float* O = l ? bufA : bufB;
        // merged fwd|rev input transform: [8192,2048] (Wih rows 2l,2l+1 contiguous)
        gemm_tn<<<dim3(2048 / 128, 64), blk, 0, stream>>>(
            Xin, Wih + (size_t)(2 * l) * G4n * Hn, Gbig,
            bih + (size_t)(2 * l) * G4n, bhh + (size_t)(2 * l) * G4n,
            Tn * Bn, 2048, Hn);
        hipMemsetAsync(O, 0, (size_t)4194304 * 4, stream);
        hipMemsetAsync(bar, 0, 64 * sizeof(unsigned), stream);
        enc_scan<<<64, blk, 0, stream>>>(
            Gbig,
            Whh + (size_t)(2 * l) * G4n * HHn, Whh + (size_t)(2 * l + 1) * G4n * HHn,
            h0 + (size_t)l * 8192, c0 + (size_t)l * 8192,
            O, lens, hx, bar);
    }

    // 3. u = transpose(bufA): [T,B,H] -> [B,T,H]
    transpose_tb<<<Bn * Tn, blk, 0, stream>>>(bufA, U);

    // 4. segment-scan input transforms
    gemm_tn<<<dim3(G4n / 128, 64), blk, 0, stream>>>(
        U, Wih_sf, G0, bih_sf, bhh_sf, Bn * Tn, G4n, Hn);
    gemm_tn<<<dim3(G4n / 128, 64), blk, 0, stream>>>(
        U, Wih_sr, G1, bih_sr, bhh_sr, Bn * Tn, G4n, Hn);

    // 5. output = bias (covers all invalid/masked slots)
    init_out<<<(Bn * Tn * Pn * NTAGn + 255) / 256, blk, 0, stream>>>(
        out, bfc, Bn * Tn * Pn * NTAGn);

    // 6. segment scans, fwd then rev, FC fused into cell kernel
    //    (k==0 needs no zero-init: seg_cell skips GT/Cs reads at k==0)
    for (int dir = 0; dir < 2; dir++) {
        const float* Whh_s = dir ? Whh_sr : Whh_sf;
        const float* Gx = dir ? G1 : G0;
        for (int k = 0; k < Pn; k++) {
            if (k > 0)
                gemm_tn<<<dim3(G4n / 128, 64), blk, 0, stream>>>(
                    Hs, Whh_s, GT, nullptr, nullptr, Bn * Tn, G4n, HHn);
            seg_cell<<<Bn * Tn, blk, 0, stream>>>(GT, Gx, Hs, Cs, Wfc, out, lens, k, dir);
        }
    }
}